// Round 2
// baseline (1602.756 us; speedup 1.0000x reference)
//
#include <hip/hip_runtime.h>
#include <stdint.h>
#include <stddef.h>

#define DEVI __device__ __forceinline__

typedef __attribute__((ext_vector_type(4))) float f32x4;
typedef __attribute__((ext_vector_type(8))) __bf16 bf16x8;
typedef __attribute__((ext_vector_type(8))) short short8;
typedef __attribute__((ext_vector_type(4))) short short4v;

static constexpr int CB = 16;
static constexpr int CC = 256;
static constexpr int CH = 80, CW = 80;
static constexpr int CS = CH * CW;        // 6400
static constexpr int CBS = CB * CS;       // 102400

DEVI uint16_t f2bf(float f) {
    uint32_t u = __builtin_bit_cast(uint32_t, f);
    u += 0x7fffu + ((u >> 16) & 1u);
    return (uint16_t)(u >> 16);
}
DEVI float bf2f(uint16_t h) {
    uint32_t u = ((uint32_t)h) << 16;
    return __builtin_bit_cast(float, u);
}
DEVI f32x4 fzero4() { f32x4 z = {0.f, 0.f, 0.f, 0.f}; return z; }

DEVI f32x4 MFMA16(short8 a, short8 b, f32x4 c) {
    return __builtin_amdgcn_mfma_f32_16x16x32_bf16(
        __builtin_bit_cast(bf16x8, a), __builtin_bit_cast(bf16x8, b), c, 0, 0, 0);
}
DEVI void gld16(const void* g, void* l) {
    __builtin_amdgcn_global_load_lds((const __attribute__((address_space(1))) void*)g,
                                     (__attribute__((address_space(3))) void*)l, 16, 0, 0);
}

// ---------------- weight prep: pack to bf16 ----------------
__global__ __launch_bounds__(256)
void k_prep(const float* wq, const float* wk, const float* wvl, const float* wvr,
            const float* lp3w, const float* rp3w,
            const float* bq_, const float* bk_, const float* bvl_, const float* bvr_,
            const float* lp3b, const float* rp3b,
            uint16_t* Wq, uint16_t* Wk, uint16_t* Wvl, uint16_t* Wvr, uint16_t* W3,
            float* bq, float* bk, float* bvl, float* bvr, float* b3) {
    int i = blockIdx.x * 256 + threadIdx.x;   // 0..262143
    {
        int sub = i >> 16, r = i & 65535;
        const float* src = sub == 0 ? wq : sub == 1 ? wk : sub == 2 ? wvl : wvr;
        uint16_t* dst = sub == 0 ? Wq : sub == 1 ? Wk : sub == 2 ? Wvl : Wvr;
        dst[r] = f2bf(src[r]);                // [256][256] row-major (o,k)
    }
    if (i < 131072) {
        int o = i >> 9, k = i & 511;          // W3: [256][512], [o][0:256]=lp3, [256:512]=rp3
        W3[i] = f2bf(k < 256 ? lp3w[o * 256 + k] : rp3w[o * 256 + (k - 256)]);
    }
    if (i < 256) {
        bq[i] = bq_[i]; bk[i] = bk_[i]; bvl[i] = bvl_[i]; bvr[i] = bvr_[i];
        b3[i] = lp3b[i] + rp3b[i];
    }
}

// ---------------- transpose NCHW f32 -> chunk-local [bl*CS+s][256] bf16 ----------------
__global__ __launch_bounds__(256)
void k_transpose(const float* __restrict__ x, uint16_t* __restrict__ xt, int b0) {
    __shared__ uint16_t tile[64][65];
    const int bid = blockIdx.x;               // bl*400 + ct*100 + st
    const int bl = bid / 400, r0 = bid % 400, ct = r0 / 100, st = r0 % 100;
    const int c0 = ct * 64, s0 = st * 64;
    const int t = threadIdx.x;
    {
        const int sl = t & 63, cq = t >> 6;
        #pragma unroll
        for (int i = 0; i < 16; ++i) {
            int cl = cq * 16 + i;
            tile[cl][sl] = f2bf(x[((size_t)((b0 + bl) * 256 + c0 + cl)) * CS + s0 + sl]);
        }
    }
    __syncthreads();
    {
        const int cl = t & 63, sq = t >> 6;
        #pragma unroll
        for (int i = 0; i < 16; ++i) {
            int sl = sq * 16 + i;
            xt[((size_t)(bl * CS + s0 + sl)) * 256 + c0 + cl] = tile[cl][sl];
        }
    }
}

// ---------------- MFMA GEMM: D[m][n] = sum_k A[m][k]*B[n][k] + bias ----------------
// A: [*, KT] bf16 row-major (m rows); B: [*, KT] bf16 row-major (n rows).
// OUTMODE 0: D[m*ldd + n]; OUTMODE 1: channel-first fold D[(n/CS)*CC*CS + m*CS + n%CS]
// BIASMODE 0: bias[n]; 1: bias[m]
template<int NSTEPS, int OUTMODE, int BIASMODE>
__global__ __launch_bounds__(256)
void k_gemm(const uint16_t* __restrict__ A, const uint16_t* __restrict__ Bm,
            const float* __restrict__ bias, uint16_t* __restrict__ D, int ldd) {
    constexpr int KT = NSTEPS * 64;
    __shared__ uint16_t la[128 * 64];
    __shared__ uint16_t lb[128 * 64];
    const int m0 = blockIdx.x * 128, n0 = blockIdx.y * 128;
    const int t = threadIdx.x, lane = t & 63, wv = t >> 6;
    const int lrow = lane & 15, lkg = lane >> 4;
    const int wm = (wv >> 1) * 64, wn = (wv & 1) * 64;
    f32x4 acc[4][4];
    #pragma unroll
    for (int i = 0; i < 4; ++i)
        #pragma unroll
        for (int j = 0; j < 4; ++j) acc[i][j] = fzero4();

    for (int kt = 0; kt < NSTEPS; ++kt) {
        if (kt) __syncthreads();
        #pragma unroll
        for (int q = 0; q < 4; ++q) {
            int slot = (q * 4 + wv) * 64;       // wave-uniform 16B slot base
            int off = (slot + lane) * 16;       // this lane's byte
            int row = off >> 7;                 // 128B rows
            int s8 = (off >> 4) & 7;
            int c8 = s8 ^ (row & 7);            // pre-swizzled source (G21)
            gld16(A + (size_t)(m0 + row) * KT + kt * 64 + c8 * 8, la + (size_t)slot * 8);
            gld16(Bm + (size_t)(n0 + row) * KT + kt * 64 + c8 * 8, lb + (size_t)slot * 8);
        }
        __syncthreads();                        // drains vmcnt(0) per HIP semantics
        short8 af[2][4], bg[2][4];
        #pragma unroll
        for (int ks = 0; ks < 2; ++ks) {
            int kb2 = (ks * 32 + lkg * 8) * 2;  // byte offset of k-run
            #pragma unroll
            for (int i = 0; i < 4; ++i) {
                int ra = wm + i * 16 + lrow;
                af[ks][i] = *(const short8*)((const char*)la + ((ra * 128 + kb2) ^ ((ra & 7) << 4)));
                int rb = wn + i * 16 + lrow;
                bg[ks][i] = *(const short8*)((const char*)lb + ((rb * 128 + kb2) ^ ((rb & 7) << 4)));
            }
        }
        #pragma unroll
        for (int ks = 0; ks < 2; ++ks)
            #pragma unroll
            for (int i = 0; i < 4; ++i)
                #pragma unroll
                for (int j = 0; j < 4; ++j)
                    acc[i][j] = MFMA16(af[ks][i], bg[ks][j], acc[i][j]);
    }
    const int bfold = n0 / CS;                  // constant per block (CS % 128 == 0)
    #pragma unroll
    for (int i = 0; i < 4; ++i) {
        #pragma unroll
        for (int j = 0; j < 4; ++j) {
            int mr0 = m0 + wm + i * 16 + lkg * 4;
            int nc = n0 + wn + j * 16 + lrow;
            #pragma unroll
            for (int r = 0; r < 4; ++r) {
                float v = acc[i][j][r] + (BIASMODE == 0 ? bias[nc] : bias[mr0 + r]);
                size_t oa;
                if (OUTMODE == 0) oa = (size_t)(mr0 + r) * (size_t)ldd + nc;
                else oa = (size_t)bfold * (size_t)(CC * CS - CS) + (size_t)(mr0 + r) * CS + nc;
                D[oa] = f2bf(v);
            }
        }
    }
}

// ---------------- depthwise 3x3 (zero pad) + bias, channel-last [*,256] ----------------
__global__ __launch_bounds__(256)
void k_dw(const uint16_t* __restrict__ src, const float* __restrict__ w2,
          const float* __restrict__ b2, uint16_t* __restrict__ dst) {
    __shared__ uint16_t tile[10][80][32];
    const int bx = blockIdx.x;                  // bl*10 + ht
    const int b = bx / 10, ht = bx % 10;
    const int cc = blockIdx.y;                  // 0..7 (32-channel group)
    const int t = threadIdx.x;
    const int h0 = ht * 8;
    for (int idx = t; idx < 10 * 80 * 8; idx += 256) {
        int c4 = idx & 7, x = (idx >> 3) % 80, y = idx / 640;
        int gy = h0 - 1 + y;
        short4v v = {0, 0, 0, 0};
        if (gy >= 0 && gy < 80)
            v = *(const short4v*)(src + ((size_t)(b * CS + gy * 80 + x)) * 256 + cc * 32 + c4 * 4);
        *(short4v*)(&tile[y][x][c4 * 4]) = v;
    }
    __syncthreads();
    const int c = t & 31, xg = t >> 5;
    const int cg = cc * 32 + c;
    float w9[9];
    #pragma unroll
    for (int i2 = 0; i2 < 9; ++i2) w9[i2] = w2[cg * 9 + i2];
    const float bb = b2[cg];
    for (int oy = 0; oy < 8; ++oy) {
        #pragma unroll
        for (int xk = 0; xk < 10; ++xk) {
            int x = xg + 8 * xk;
            float a = bb;
            #pragma unroll
            for (int dy = 0; dy < 3; ++dy)
                #pragma unroll
                for (int dx = 0; dx < 3; ++dx) {
                    int xx = x + dx - 1;
                    if (xx >= 0 && xx < 80)
                        a += w9[dy * 3 + dx] * bf2f(tile[oy + dy][xx][c]);
                }
            dst[((size_t)(b * CS + (h0 + oy) * 80 + x)) * 256 + cg] = f2bf(a);
        }
    }
}

// ---------------- per-row cross attention: one block per (b_local,h) ----------------
__global__ __launch_bounds__(256)
void k_attn(const uint16_t* __restrict__ Q, const uint16_t* __restrict__ K,
            const uint16_t* __restrict__ Vl, const uint16_t* __restrict__ Vr,
            uint16_t* __restrict__ F) {
    __shared__ __align__(16) char sm[59904];
    uint16_t* const Prow = (uint16_t*)sm;                   // [80][104] bf16
    uint16_t* const Pcol = (uint16_t*)(sm + 16640);         // [80][104]
    float*    const attn = (float*)(sm + 33280);            // [80][81] f32
    uint16_t* const VrT  = (uint16_t*)(sm + 33280);         // phase C: [64][104]
    uint16_t* const VlT  = (uint16_t*)(sm + 33280 + 13312); // [64][104]
    const int bh = blockIdx.x;
    const size_t gbase = (size_t)bh * 80 * 256;
    const int t = threadIdx.x, lane = t & 63, wv = t >> 6;
    const int lrow = lane & 15, lkg = lane >> 4;

    // ---- phase A: attn = (Ql . Kr^T) * SCALE via MFMA, Q|K staged in 64-ch chunks
    f32x4 acc[7];
    #pragma unroll
    for (int u = 0; u < 7; ++u) acc[u] = fzero4();
    for (int kc = 0; kc < 4; ++kc) {
        if (kc) __syncthreads();
        #pragma unroll
        for (int q = 0; q < 5; ++q) {
            int slot = (q * 4 + wv) * 64;
            int off = (slot + lane) * 16;
            int row = off >> 7;               // 0..79 = Ql rows, 80..159 = Kr rows
            int s8 = (off >> 4) & 7;
            int c8 = s8 ^ (row & 7);
            const uint16_t* g = (row < 80)
                ? (Q + gbase + (size_t)row * 256 + kc * 64 + c8 * 8)
                : (K + gbase + (size_t)(row - 80) * 256 + kc * 64 + c8 * 8);
            gld16(g, (uint16_t*)sm + (size_t)slot * 8);
        }
        __syncthreads();
        #pragma unroll
        for (int ks = 0; ks < 2; ++ks) {
            int kb2 = (ks * 32 + lkg * 8) * 2;
            #pragma unroll
            for (int u = 0; u < 7; ++u) {
                int tt = wv + 4 * u;
                if (tt < 25) {
                    int mt = tt / 5, nt = tt % 5;
                    int ra = mt * 16 + lrow;
                    short8 a = *(const short8*)((const char*)sm + ((ra * 128 + kb2) ^ ((ra & 7) << 4)));
                    int rb = 80 + nt * 16 + lrow;
                    short8 b = *(const short8*)((const char*)sm + ((rb * 128 + kb2) ^ ((rb & 7) << 4)));
                    acc[u] = MFMA16(a, b, acc[u]);
                }
            }
        }
    }
    __syncthreads();
    #pragma unroll
    for (int u = 0; u < 7; ++u) {
        int tt = wv + 4 * u;
        if (tt < 25) {
            int mt = tt / 5, nt = tt % 5;
            int mrow = mt * 16 + lkg * 4, ncol = nt * 16 + lrow;
            #pragma unroll
            for (int r = 0; r < 4; ++r) attn[(mrow + r) * 81 + ncol] = acc[u][r] * 0.0625f;
        }
    }
    __syncthreads();
    // ---- phase B: row softmax (threads 0..79) and column softmax (threads 128..207)
    if (t < 80) {
        const int rr = t;
        float mx = -1e30f;
        for (int v = 0; v < 80; ++v) mx = fmaxf(mx, attn[rr * 81 + v]);
        float s = 0.f;
        for (int v = 0; v < 80; ++v) s += __expf(attn[rr * 81 + v] - mx);
        float inv = 1.f / s;
        for (int v = 0; v < 80; ++v) Prow[rr * 104 + v] = f2bf(__expf(attn[rr * 81 + v] - mx) * inv);
        for (int v = 80; v < 96; ++v) Prow[rr * 104 + v] = 0;
    } else if (t >= 128 && t < 208) {
        const int vv = t - 128;
        float mx = -1e30f;
        for (int w = 0; w < 80; ++w) mx = fmaxf(mx, attn[w * 81 + vv]);
        float s = 0.f;
        for (int w = 0; w < 80; ++w) s += __expf(attn[w * 81 + vv] - mx);
        float inv = 1.f / s;
        for (int w = 0; w < 80; ++w) Pcol[vv * 104 + w] = f2bf(__expf(attn[w * 81 + vv] - mx) * inv);
        for (int w = 80; w < 96; ++w) Pcol[vv * 104 + w] = 0;
    }
    // ---- phase C: F_r2l = Prow*Vr, F_l2r = Pcol*Vl (V transposed in LDS, 64-ch chunks)
    for (int nc4 = 0; nc4 < 4; ++nc4) {
        __syncthreads();
        {
            int cl = t & 63, vg = t >> 6;
            const uint16_t* gr = Vr + gbase + nc4 * 64 + cl;
            const uint16_t* gl = Vl + gbase + nc4 * 64 + cl;
            #pragma unroll
            for (int vb = 0; vb < 5; ++vb) {
                int v0 = vg * 20 + vb * 4;
                short4v pr, pl;
                #pragma unroll
                for (int e = 0; e < 4; ++e) {
                    pr[e] = (short)gr[(size_t)(v0 + e) * 256];
                    pl[e] = (short)gl[(size_t)(v0 + e) * 256];
                }
                *(short4v*)(VrT + cl * 104 + v0) = pr;
                *(short4v*)(VlT + cl * 104 + v0) = pl;
            }
            if (vg == 0) {
                short4v z = {0, 0, 0, 0};
                #pragma unroll
                for (int v = 80; v < 96; v += 4) {
                    *(short4v*)(VrT + cl * 104 + v) = z;
                    *(short4v*)(VlT + cl * 104 + v) = z;
                }
            }
        }
        __syncthreads();
        #pragma unroll
        for (int k10 = 0; k10 < 10; ++k10) {
            int jj = wv + 4 * k10;               // 0..39 = 2 mats x 5 mt x 4 ntl
            int mat = jj / 20, rest = jj % 20, mt = rest / 4, ntl = rest % 4;
            const uint16_t* P = mat ? Pcol : Prow;
            const uint16_t* VT = mat ? VlT : VrT;
            f32x4 o = fzero4();
            #pragma unroll
            for (int ks = 0; ks < 3; ++ks) {
                int kb = ks * 32 + lkg * 8;
                short8 a = *(const short8*)(P + (mt * 16 + lrow) * 104 + kb);
                short8 b = *(const short8*)(VT + (ntl * 16 + lrow) * 104 + kb);
                o = MFMA16(a, b, o);
            }
            int mrow = mt * 16 + lkg * 4;
            int ncol = nc4 * 64 + ntl * 16 + lrow;
            #pragma unroll
            for (int r = 0; r < 4; ++r)
                F[((size_t)bh * 80 + mrow + r) * 512 + (size_t)mat * 256 + ncol] = f2bf(o[r]);
        }
    }
}

// ---------------- final: grouped 7x7 (reflect pad) + double sigmoid + blend ----------------
__global__ __launch_bounds__(256)
void k_final(const float* __restrict__ xl, const float* __restrict__ xr,
             const uint16_t* __restrict__ pat, const float* __restrict__ paw,
             const float* __restrict__ pab, float* __restrict__ out, int b0) {
    __shared__ uint16_t ti[8][14][88];
    __shared__ uint16_t tp[8][14][88];
    __shared__ float wsm[8][98];
    __shared__ float bsm[8];
    const int bid = blockIdx.x;               // bl*320 + cc*10 + ht
    const int bl = bid / 320, r0 = bid % 320, cc = r0 / 10, ht = r0 % 10;
    const int bg = b0 + bl;
    const int c0 = cc * 8, h0 = ht * 8;
    const int t = threadIdx.x;
    for (int i = t; i < 8 * 98; i += 256) wsm[i / 98][i % 98] = paw[(c0 + i / 98) * 98 + (i % 98)];
    if (t < 8) bsm[t] = pab[c0 + t];
    for (int i = t; i < 8 * 14 * 86; i += 256) {
        int x = i % 86, y = (i / 86) % 14, c = i / (86 * 14);
        int gx = x - 3, gy = h0 + y - 3;
        gx = gx < 0 ? -gx : (gx > 79 ? 158 - gx : gx);
        gy = gy < 0 ? -gy : (gy > 79 ? 158 - gy : gy);
        size_t cfg = ((size_t)(bg * 256 + c0 + c)) * CS + gy * 80 + gx;
        size_t cfl = ((size_t)(bl * 256 + c0 + c)) * CS + gy * 80 + gx;
        ti[c][y][x] = f2bf(xl[cfg] + xr[cfg]);
        tp[c][y][x] = pat[cfl];
    }
    __syncthreads();
    for (int o = t; o < 8 * 8 * 80; o += 256) {
        int w = o % 80, y = (o / 80) % 8, c = o / 640;
        float acc = bsm[c];
        #pragma unroll
        for (int ky = 0; ky < 7; ++ky)
            #pragma unroll
            for (int kx = 0; kx < 7; ++kx) {
                acc += wsm[c][ky * 7 + kx] * bf2f(ti[c][y + ky][w + kx])
                     + wsm[c][49 + ky * 7 + kx] * bf2f(tp[c][y + ky][w + kx]);
            }
        float a = 1.f / (1.f + __expf(-acc));
        a = 1.f / (1.f + __expf(-a));
        size_t cfg = ((size_t)(bg * 256 + c0 + c)) * CS + (h0 + y) * 80 + w;
        float vl = xl[cfg], vr = xr[cfg];
        out[cfg] = a * vl + (1.f - a) * vr;
    }
}

extern "C" void kernel_launch(void* const* d_in, const int* in_sizes, int n_in,
                              void* d_out, int out_size, void* d_ws, size_t ws_size,
                              hipStream_t stream) {
    const float* xl = (const float*)d_in[0];
    const float* xr = (const float*)d_in[1];
    const float* lp1_w1 = (const float*)d_in[2];
    const float* lp1_b1 = (const float*)d_in[3];
    const float* lp1_w2 = (const float*)d_in[4];
    const float* lp1_b2 = (const float*)d_in[5];
    const float* rp1_w1 = (const float*)d_in[6];
    const float* rp1_b1 = (const float*)d_in[7];
    const float* rp1_w2 = (const float*)d_in[8];
    const float* rp1_b2 = (const float*)d_in[9];
    const float* lp2_w1 = (const float*)d_in[10];
    const float* lp2_b1 = (const float*)d_in[11];
    const float* lp2_w2 = (const float*)d_in[12];
    const float* lp2_b2 = (const float*)d_in[13];
    const float* rp2_w1 = (const float*)d_in[14];
    const float* rp2_b1 = (const float*)d_in[15];
    const float* rp2_w2 = (const float*)d_in[16];
    const float* rp2_b2 = (const float*)d_in[17];
    const float* lp3_w = (const float*)d_in[18];
    const float* lp3_b = (const float*)d_in[19];
    const float* rp3_w = (const float*)d_in[20];
    const float* rp3_b = (const float*)d_in[21];
    const float* pa_w = (const float*)d_in[22];
    const float* pa_b = (const float*)d_in[23];

    char* ws = (char*)d_ws;
    // ---- packed weights at the front (< 1 MB)
    uint16_t* Wq  = (uint16_t*)(ws + 0);       // lp1_w1 [256][256] bf16
    uint16_t* Wk  = (uint16_t*)(ws + 131072);  // rp1_w1
    uint16_t* Wvl = (uint16_t*)(ws + 262144);  // lp2_w1
    uint16_t* Wvr = (uint16_t*)(ws + 393216);  // rp2_w1
    uint16_t* W3  = (uint16_t*)(ws + 524288);  // [256][512] = [lp3|rp3]
    float* bq  = (float*)(ws + 786432);
    float* bk  = (float*)(ws + 787456);
    float* bvl = (float*)(ws + 788480);
    float* bvr = (float*)(ws + 789504);
    float* b3  = (float*)(ws + 790528);
    char* data = ws + (1 << 20);

    // ---- per-batch slot = 6400*256 bf16 = 3,276,800 B; 6 slots live at peak.
    // Adaptive batch-chunking: bc chosen from ws_size (constant across calls).
    const size_t U = (size_t)CS * 256 * 2;
    int bc = 16;
    while (bc > 1 && (size_t)(1 << 20) + 6 * U * (size_t)bc > ws_size) bc >>= 1;

    k_prep<<<dim3(1024), dim3(256), 0, stream>>>(
        lp1_w1, rp1_w1, lp2_w1, rp2_w1, lp3_w, rp3_w,
        lp1_b1, rp1_b1, lp2_b1, rp2_b1, lp3_b, rp3_b,
        Wq, Wk, Wvl, Wvr, W3, bq, bk, bvl, bvr, b3);

    uint16_t* X   = (uint16_t*)(data);              // slot 0
    uint16_t* Yt  = (uint16_t*)(data + U * bc);     // slot 1
    uint16_t* Qb  = (uint16_t*)(data + 2 * U * bc); // slot 2
    uint16_t* Kb  = (uint16_t*)(data + 3 * U * bc); // slot 3
    uint16_t* Vlb = (uint16_t*)(data + 4 * U * bc); // slot 4
    uint16_t* Vrb = (uint16_t*)(data + 5 * U * bc); // slot 5
    uint16_t* Fb  = (uint16_t*)(data);              // slots 0-1 (X,Yt dead by attn)
    uint16_t* Pat = (uint16_t*)(data + 2 * U * bc); // slot 2 (Q dead by gemm3)

    for (int b0 = 0; b0 < CB; b0 += bc) {
        // left: Q = dw(lp1(x_l)), Vl = dw(lp2(x_l))
        k_transpose<<<dim3(bc * 400), dim3(256), 0, stream>>>(xl, X, b0);
        k_gemm<4, 0, 0><<<dim3(bc * 50, 2), dim3(256), 0, stream>>>(X, Wq, bq, Yt, 256);
        k_dw<<<dim3(bc * 10, 8), dim3(256), 0, stream>>>(Yt, lp1_w2, lp1_b2, Qb);
        k_gemm<4, 0, 0><<<dim3(bc * 50, 2), dim3(256), 0, stream>>>(X, Wvl, bvl, Yt, 256);
        k_dw<<<dim3(bc * 10, 8), dim3(256), 0, stream>>>(Yt, lp2_w2, lp2_b2, Vlb);
        // right: K = dw(rp1(x_r)), Vr = dw(rp2(x_r))
        k_transpose<<<dim3(bc * 400), dim3(256), 0, stream>>>(xr, X, b0);
        k_gemm<4, 0, 0><<<dim3(bc * 50, 2), dim3(256), 0, stream>>>(X, Wk, bk, Yt, 256);
        k_dw<<<dim3(bc * 10, 8), dim3(256), 0, stream>>>(Yt, rp1_w2, rp1_b2, Kb);
        k_gemm<4, 0, 0><<<dim3(bc * 50, 2), dim3(256), 0, stream>>>(X, Wvr, bvr, Yt, 256);
        k_dw<<<dim3(bc * 10, 8), dim3(256), 0, stream>>>(Yt, rp2_w2, rp2_b2, Vrb);
        // cross attention -> F = [F_r2l | F_l2r] channel-last [bc*CS][512]
        k_attn<<<dim3(bc * 80), dim3(256), 0, stream>>>(Qb, Kb, Vlb, Vrb, Fb);
        // output projections (transposed GEMM) -> pattn1 channel-first bf16
        k_gemm<8, 1, 1><<<dim3(2, bc * 50), dim3(256), 0, stream>>>(W3, Fb, b3, Pat, 0);
        // grouped 7x7 reflect conv + double sigmoid + blend
        k_final<<<dim3(bc * 320), dim3(256), 0, stream>>>(xl, xr, Pat, pa_w, pa_b,
                                                          (float*)d_out, b0);
    }
}